// Round 7
// baseline (445.964 us; speedup 1.0000x reference)
//
#include <hip/hip_runtime.h>
#include <stdint.h>

// Problem: B=8, S=1024, NX=1024, H=16, D=64 (GPT-2 attention block)
// out = [ a: B*S*NX ][ present_k: B*H*S*D ][ present_v: B*H*S*D ]
// Input/output dtype sniffed at runtime (fp32 vs bf16); internals bf16.

#define BB 8
#define SS 1024
#define NXX 1024
#define NH 16
#define HD 64

typedef __bf16 bf16x8 __attribute__((ext_vector_type(8)));
typedef float  floatx4 __attribute__((ext_vector_type(4)));
typedef unsigned short ushort8 __attribute__((ext_vector_type(8)));
typedef unsigned short ushortx4 __attribute__((ext_vector_type(4)));  // 'ushort4' collides with HIP builtin

__device__ inline float bf2f(unsigned short u) {
    unsigned int x = ((unsigned int)u) << 16;
    float f;
    __builtin_memcpy(&f, &x, 4);
    return f;
}
__device__ inline unsigned short f2bf(float f) {
    unsigned int u;
    __builtin_memcpy(&u, &f, 4);
    u += 0x7FFFu + ((u >> 16) & 1u);  // RNE
    return (unsigned short)(u >> 16);
}

// async global->LDS, 16B per lane (dest = wave-uniform base + lane*16)
__device__ inline void gload_lds16(const unsigned short* g, unsigned short* l) {
    __builtin_amdgcn_global_load_lds(
        (const __attribute__((address_space(1))) void*)g,
        (__attribute__((address_space(3))) void*)l, 16, 0, 0);
}

// ---------------- dtype sniff: flag=1 if data is fp32, 0 if bf16 ----------------
__global__ void sniff_k(const unsigned short* __restrict__ x, int* __restrict__ flag) {
    if (threadIdx.x == 0 && blockIdx.x == 0) {
        int g = 0;
        for (int i = 0; i < 512; i++) {
            float f = bf2f(x[i]);
            float a = fabsf(f);
            if (!(a <= 1e4f)) g++;
            else if (f != 0.f && a < 1e-35f) g++;
        }
        *flag = (g > 16) ? 1 : 0;
    }
}

// ---------------- convert x -> bf16 (8 elems/thread) ----------------
__global__ __launch_bounds__(256) void convert_x(
    const void* __restrict__ in, unsigned short* __restrict__ out,
    const int* __restrict__ flagp) {
    const int f32 = *flagp;
    const size_t i = ((size_t)blockIdx.x * 256 + threadIdx.x) * 8;
    if (f32) {
        const floatx4* p = (const floatx4*)((const float*)in + i);
        floatx4 f0 = p[0], f1 = p[1];
        ushort8 u;
#pragma unroll
        for (int j = 0; j < 4; j++) { u[j] = f2bf(f0[j]); u[4 + j] = f2bf(f1[j]); }
        *(ushort8*)(out + i) = u;
    } else {
        *(ushort8*)(out + i) = *(const ushort8*)((const unsigned short*)in + i);
    }
}

// ---------------- transpose+convert: out_bf16[C][R] = in[R][C] ----------------
__global__ __launch_bounds__(256) void transpose_k(
    const void* __restrict__ in, unsigned short* __restrict__ out,
    int R, int C, const int* __restrict__ flagp) {
    const int f32 = *flagp;
    __shared__ unsigned short tile[32][33];
    int c0 = blockIdx.x * 32, r0 = blockIdx.y * 32;
    int tx = threadIdx.x & 31, ty = threadIdx.x >> 5;  // 32 x 8
    if (f32) {
        const float* inf = (const float*)in;
#pragma unroll
        for (int i = ty; i < 32; i += 8)
            tile[i][tx] = f2bf(inf[(r0 + i) * C + c0 + tx]);
    } else {
        const unsigned short* inu = (const unsigned short*)in;
#pragma unroll
        for (int i = ty; i < 32; i += 8)
            tile[i][tx] = inu[(r0 + i) * C + c0 + tx];
    }
    __syncthreads();
#pragma unroll
    for (int i = ty; i < 32; i += 8)
        out[(c0 + i) * R + r0 + tx] = tile[tx][i];
}

// ---------------- GEMM: C[M,N] = A[M,K] @ Bt[N,K]^T + bias[N] ----------------
// A, Bt: bf16. Staging via global_load_lds (16B/lane, m97 structure).
// MODE 0: writes `a` region of d_out in flag dtype.
// MODE 1: block-uniform section (col0>>10): q / k / v epilogues.
//   v-blocks: vbfT written via LDS transpose (coalesced ushort8, sperm order).
template <int MODE>
__global__ __launch_bounds__(256) void gemm_bt(
    const unsigned short* __restrict__ A,
    const unsigned short* __restrict__ Bt,
    const void* __restrict__ bias,
    void* __restrict__ outbase,
    unsigned short* __restrict__ q_ws,
    unsigned short* __restrict__ kbf,
    unsigned short* __restrict__ vbfT,
    int M, int N, int K, const int* __restrict__ flagp) {
    // shared: As[128*32] | Bs[128*32] unioned with tbuf[128][72] (epilogue)
    __shared__ __align__(16) unsigned short smem[9216];
    unsigned short* As = smem;
    unsigned short* Bs = smem + 4096;
    unsigned short (*tbuf)[72] = (unsigned short(*)[72])smem;

    const int f32 = *flagp;
    const int tid  = threadIdx.x;
    const int lane = tid & 63;
    const int wave = tid >> 6;
    const int wr = wave >> 1, wc = wave & 1;
    const int l15 = lane & 15;
    const int quad = lane >> 4;
    const int row0 = blockIdx.y * 128;
    const int col0 = blockIdx.x * 128;

    floatx4 acc[4][4];
    floatx4 zz = {0.f, 0.f, 0.f, 0.f};
#pragma unroll
    for (int i = 0; i < 4; i++)
#pragma unroll
        for (int j = 0; j < 4; j++) acc[i][j] = zz;

    const int lrow = lane >> 2;
    const int lcol = (lane & 3) * 8;
    const unsigned short* Ag = A  + (size_t)(row0 + wave * 32 + lrow) * K + lcol;
    const unsigned short* Bg = Bt + (size_t)(col0 + wave * 32 + lrow) * K + lcol;
    unsigned short* Asl0 = &As[(wave * 32) * 32];
    unsigned short* Asl1 = &As[(wave * 32 + 16) * 32];
    unsigned short* Bsl0 = &Bs[(wave * 32) * 32];
    unsigned short* Bsl1 = &Bs[(wave * 32 + 16) * 32];

    for (int k0 = 0; k0 < K; k0 += 32) {
        gload_lds16(Ag + k0, Asl0);
        gload_lds16(Ag + k0 + (size_t)16 * K, Asl1);
        gload_lds16(Bg + k0, Bsl0);
        gload_lds16(Bg + k0 + (size_t)16 * K, Bsl1);
        __syncthreads();

        bf16x8 af[4], bfr[4];
#pragma unroll
        for (int mi = 0; mi < 4; mi++)
            af[mi] = *(const bf16x8*)&As[(wr * 64 + mi * 16 + l15) * 32 + quad * 8];
#pragma unroll
        for (int ni = 0; ni < 4; ni++)
            bfr[ni] = *(const bf16x8*)&Bs[(wc * 64 + ni * 16 + l15) * 32 + quad * 8];
#pragma unroll
        for (int mi = 0; mi < 4; mi++)
#pragma unroll
            for (int ni = 0; ni < 4; ni++)
                acc[mi][ni] = __builtin_amdgcn_mfma_f32_16x16x32_bf16(af[mi], bfr[ni], acc[mi][ni], 0, 0, 0);
        __syncthreads();
    }

    // bias per ni-frag
    float bv[4];
#pragma unroll
    for (int ni = 0; ni < 4; ni++) {
        const int colb = col0 + wc * 64 + ni * 16 + l15;
        bv[ni] = f32 ? ((const float*)bias)[colb] : bf2f(((const unsigned short*)bias)[colb]);
    }

    if (MODE == 0) {
#pragma unroll
        for (int mi = 0; mi < 4; mi++)
#pragma unroll
            for (int ni = 0; ni < 4; ni++) {
                const int colb = col0 + wc * 64 + ni * 16 + l15;
#pragma unroll
                for (int i = 0; i < 4; i++) {
                    const int row = row0 + wr * 64 + mi * 16 + quad * 4 + i;
                    const float val = acc[mi][ni][i] + bv[ni];
                    const size_t idx = (size_t)row * N + colb;
                    if (f32) ((float*)outbase)[idx] = val;
                    else     ((unsigned short*)outbase)[idx] = f2bf(val);
                }
            }
        return;
    }

    // MODE 1: section is block-uniform (col tile never straddles 1024 boundary)
    const int sec = col0 >> 10;
    const size_t esz = f32 ? 4 : 2;
    const int b = row0 >> 10;          // single b per block (128 | 1024)
    const int s0 = row0 & 1023;

    if (sec == 0) {
        // ---- q -> q_ws bf16 [bh][s][d] ----
#pragma unroll
        for (int mi = 0; mi < 4; mi++)
#pragma unroll
            for (int ni = 0; ni < 4; ni++) {
                const int colb = col0 + wc * 64 + ni * 16 + l15;
                const int h = (colb & 1023) >> 6, d = colb & 63;
#pragma unroll
                for (int i = 0; i < 4; i++) {
                    const int s = s0 + wr * 64 + mi * 16 + quad * 4 + i;
                    q_ws[(size_t)((b * NH + h) * SS + s) * HD + d] = f2bf(acc[mi][ni][i] + bv[ni]);
                }
            }
    } else if (sec == 1) {
        // ---- k -> d_out (flag dtype) + kbf bf16, both [bh][s][d] ----
        char* kbase = (char*)outbase + (size_t)(BB * SS * NXX) * esz;
#pragma unroll
        for (int mi = 0; mi < 4; mi++)
#pragma unroll
            for (int ni = 0; ni < 4; ni++) {
                const int colb = col0 + wc * 64 + ni * 16 + l15;
                const int h = (colb & 1023) >> 6, d = colb & 63;
#pragma unroll
                for (int i = 0; i < 4; i++) {
                    const int s = s0 + wr * 64 + mi * 16 + quad * 4 + i;
                    const float val = acc[mi][ni][i] + bv[ni];
                    const size_t idx = (size_t)((b * NH + h) * SS + s) * HD + d;
                    if (f32) ((float*)kbase)[idx] = val;
                    else     ((unsigned short*)kbase)[idx] = f2bf(val);
                    kbf[idx] = f2bf(val);
                }
            }
    } else {
        // ---- v -> d_out (flag dtype, [bh][s][d]) + vbfT bf16 [bh][d][sperm] ----
        char* vbase = (char*)outbase + (size_t)(2 * BB * SS * NXX) * esz;
        const int h0 = (col0 & 1023) >> 6;
#pragma unroll
        for (int mi = 0; mi < 4; mi++)
#pragma unroll
            for (int ni = 0; ni < 4; ni++) {
                const int colb = col0 + wc * 64 + ni * 16 + l15;
                const int h = (colb & 1023) >> 6, d = colb & 63;
#pragma unroll
                for (int i = 0; i < 4; i++) {
                    const int s = s0 + wr * 64 + mi * 16 + quad * 4 + i;
                    const float val = acc[mi][ni][i] + bv[ni];
                    const size_t idx = (size_t)((b * NH + h) * SS + s) * HD + d;
                    if (f32) ((float*)vbase)[idx] = val;
                    else     ((unsigned short*)vbase)[idx] = f2bf(val);
                }
            }
        // LDS transpose: two row-halves of 64 (s64-block aligned), sperm order
#pragma unroll
        for (int half = 0; half < 2; half++) {
            __syncthreads();
            if (wr == half) {
#pragma unroll
                for (int mi = 0; mi < 4; mi++)
#pragma unroll
                    for (int ni = 0; ni < 4; ni++) {
                        const int c = wc * 64 + ni * 16 + l15;
#pragma unroll
                        for (int i = 0; i < 4; i++) {
                            const int r = mi * 16 + quad * 4 + i;         // 0..63
                            const int perm = ((r & 15) << 2) | (r >> 4);  // sperm within 64-block
                            tbuf[c][perm] = f2bf(acc[mi][ni][i] + bv[ni]);
                        }
                    }
            }
            __syncthreads();
            // coalesced store: 2 threads/col, 4 ushort8 chunks each
            const int col = tid >> 1;
            const int h = h0 + (col >> 6), d = col & 63;
            unsigned short* dst = vbfT + (size_t)((b * NH + h) * HD + d) * SS + s0 + half * 64;
#pragma unroll
            for (int cc = 0; cc < 4; cc++) {
                const int chunk = (tid & 1) * 4 + cc;
                *(ushort8*)(dst + chunk * 8) = *(const ushort8*)&tbuf[col][chunk * 8];
            }
        }
    }
}

// ---------------- flash attention: 4 waves/block, 2 paired Q-tiles/block ----------
// q_ws/kbf: [bh][s][d] bf16; vbfT: [bh][d][s] bf16 (key-permuted); amerged bf16.
__global__ __launch_bounds__(256) void attn(
    const unsigned short* __restrict__ q_ws,
    const unsigned short* __restrict__ kbf,
    const unsigned short* __restrict__ vbfT,
    unsigned short* __restrict__ amerged) {
    const int tid = threadIdx.x;
    const int lane = tid & 63;
    const int w = tid >> 6;
    const int l15 = lane & 15, quad = lane >> 4;
    const int blk = blockIdx.x;
    const int p = blk & 3;               // tile pair: {p, 7-p} (balanced: 18 units each)
    const int bh = blk >> 2;
    const int b = bh >> 4, h = bh & 15;

    const unsigned short* Q = q_ws + (size_t)bh * (SS * HD);
    const unsigned short* K = kbf + (size_t)bh * (SS * HD);
    const unsigned short* V = vbfT + (size_t)bh * (HD * SS);

    __shared__ __align__(16) unsigned short Ks[64][72];
    __shared__ __align__(16) unsigned short Vs[64][72];
    __shared__ __align__(16) unsigned short Pl[4][32][72];

    floatx4 zz = {0.f, 0.f, 0.f, 0.f};
    ushort8 ones_u;
#pragma unroll
    for (int j = 0; j < 8; j++) ones_u[j] = 0x3F80;  // bf16 1.0
    const bf16x8 ones = __builtin_bit_cast(bf16x8, ones_u);

    const int srow = tid >> 2;           // 0..63
    const int soff = (tid & 3) * 16;     // 0/16/32/48

#pragma unroll
    for (int tile = 0; tile < 2; tile++) {
        const int qb = tile ? (7 - p) : p;
        const int qbase = qb * 128;
        const int wrow0 = qbase + w * 32;
        const int wq_max = wrow0 + 31;
        const int jend = qbase + 128;

        bf16x8 qa[2][2];
#pragma unroll
        for (int m = 0; m < 2; m++)
#pragma unroll
            for (int t = 0; t < 2; t++)
                qa[m][t] = *(const bf16x8*)&Q[(size_t)(wrow0 + m * 16 + l15) * HD + t * 32 + quad * 8];

        floatx4 o[2][4], o5[2];
        float mrow[2][4];
#pragma unroll
        for (int m = 0; m < 2; m++) {
            o5[m] = zz;
#pragma unroll
            for (int i = 0; i < 4; i++) mrow[m][i] = -1e30f;
#pragma unroll
            for (int nf = 0; nf < 4; nf++) o[m][nf] = zz;
        }

        // prologue: stage chunk j0=0
        *(ushort8*)&Ks[srow][soff]     = *(const ushort8*)&K[(size_t)srow * HD + soff];
        *(ushort8*)&Ks[srow][soff + 8] = *(const ushort8*)&K[(size_t)srow * HD + soff + 8];
        *(ushort8*)&Vs[srow][soff]     = *(const ushort8*)&V[(size_t)srow * SS + soff];
        *(ushort8*)&Vs[srow][soff + 8] = *(const ushort8*)&V[(size_t)srow * SS + soff + 8];
        __syncthreads();

        for (int j0 = 0; j0 < jend; j0 += 64) {
            // ---- issue next chunk's global loads (overlap with compute) ----
            const bool havenext = (j0 + 64 < jend);
            ushort8 kn0, kn1, vn0, vn1;
            if (havenext) {
                kn0 = *(const ushort8*)&K[(size_t)(j0 + 64 + srow) * HD + soff];
                kn1 = *(const ushort8*)&K[(size_t)(j0 + 64 + srow) * HD + soff + 8];
                vn0 = *(const ushort8*)&V[(size_t)srow * SS + j0 + 64 + soff];
                vn1 = *(const ushort8*)&V[(size_t)srow * SS + j0 + 64 + soff + 8];
            }

            if (j0 <= wq_max) {
                // ---- scores over 64 keys ----
                floatx4 sf[2][4];
#pragma unroll
                for (int kg = 0; kg < 4; kg++) {
                    bf16x8 kb0 = *(const bf16x8*)&Ks[kg * 16 + l15][quad * 8];
                    bf16x8 kb1 = *(const bf16x8*)&Ks[kg * 16 + l15][32 + quad * 8];
#pragma unroll
                    for (int m = 0; m < 2; m++) {
                        floatx4 s = zz;
                        s = __builtin_amdgcn_mfma_f32_16x16x32_bf16(qa[m][0], kb0, s, 0, 0, 0);
                        s = __builtin_amdgcn_mfma_f32_16x16x32_bf16(qa[m][1], kb1, s, 0, 0, 0);
                        sf[m][kg] = s;
                    }
                }

                // ---- online softmax; P written permuted+packed (pos = l15*4+kg) ----
                float alpha_[2][4];
#pragma unroll
                for (int m = 0; m < 2; m++)
#pragma unroll
                    for (int i = 0; i < 4; i++) {
                        const int qrow = wrow0 + m * 16 + quad * 4 + i;
                        float pv4[4];
#pragma unroll
                        for (int kg = 0; kg < 4; kg++) {
                            const int key = j0 + kg * 16 + l15;
                            float s = sf[m][kg][i] * 0.125f;
                            if (key > qrow) s = -10000.0f;
                            pv4[kg] = s;
                        }
                        float t = fmaxf(fmaxf(pv4[0], pv4[1]), fmaxf(pv4[2], pv4[3]));
                        t = fmaxf(t, __shfl_xor(t, 1));
                        t = fmaxf(t, __shfl_xor(t, 2));
                        t = fmaxf(t, __shfl_xor(t, 4));
                        t = fmaxf(t, __shfl_xor(t, 8));
                        const float mnew = fmaxf(mrow[m][i], t);
                        alpha_[m][i] = __expf(mrow[m][i] - mnew);
                        mrow[m][i] = mnew;
                        ushortx4 pk;
#pragma unroll
                        for (int kg = 0; kg < 4; kg++)
                            pk[kg] = f2bf(__expf(pv4[kg] - mnew));
                        *(ushortx4*)&Pl[w][m * 16 + quad * 4 + i][l15 * 4] = pk;
                    }

                // ---- rescale o and o5 (running row-sum) ----
#pragma unroll
                for (int m = 0; m < 2; m++) {
#pragma unroll
                    for (int i = 0; i < 4; i++) o5[m][i] *= alpha_[m][i];
#pragma unroll
                    for (int nf = 0; nf < 4; nf++)
#pragma unroll
                        for (int i = 0; i < 4; i++) o[m][nf][i] *= alpha_[m][i];
                }

                // ---- P A-frags (wave-private LDS round trip) ----
                bf16x8 pa[2][2];
#pragma unroll
                for (int m = 0; m < 2; m++) {
                    pa[m][0] = *(const bf16x8*)&Pl[w][m * 16 + l15][quad * 8];
                    pa[m][1] = *(const bf16x8*)&Pl[w][m * 16 + l15][32 + quad * 8];
                }

                // ---- l via ones-MFMA; PV ----
#pragma unroll
                for (int m = 0; m < 2; m++) {
                    o5[m] = __builtin_amdgcn_mfma_f32_16x16x32_bf16(pa[m][0], ones, o5[m], 0, 0, 0);
                    o5[m] = __builtin_amdgcn_mfma_f32_16x16x32_bf16(pa[m][1], ones, o5[m], 0, 0, 0);
                }
#pragma unroll
                for (int nf = 0; nf < 4; nf++) {
                    bf16x8 vb0 = *(const bf16x8*)&Vs[nf * 16 + l15][quad * 8];
                    bf16x8 vb1 = *(const bf16x8*)&Vs[nf * 16 + l15][32 + quad * 8];
#pragma unroll
                    for (int m = 0; m < 2; m++) {
                        o[m][nf] = __builtin_amdgcn_mfma_f32_16x16x32_bf16(pa[m][0], vb0, o[m][nf], 0, 0, 0);
                        o[m][nf] = __builtin_amdgcn_mfma_f32_16x16x32_bf16(pa[m][1], vb1, o[m][nf], 0, 0, 0);
                    }
                }
            }
            __syncthreads();
            if (havenext) {
                *(ushort8*)&Ks[srow][soff]     = kn0;
                *(ushort8*)&Ks[srow][soff + 8] = kn1;
                *(ushort8*)&Vs[srow][soff]     = vn0;
                *(ushort8*)&Vs[srow][soff + 8] = vn1;
            }
            __syncthreads();
        }

        // ---- epilogue: l sits replicated in o5[m][i] across l15 lanes ----
#pragma unroll
        for (int m = 0; m < 2; m++)
#pragma unroll
            for (int nf = 0; nf < 4; nf++)
#pragma unroll
                for (int i = 0; i < 4; i++) {
                    const int s = wrow0 + m * 16 + quad * 4 + i;
                    amerged[(size_t)(b * SS + s) * NXX + h * HD + nf * 16 + l15] =
                        f2bf(o[m][nf][i] / o5[m][i]);
                }
        __syncthreads();  // protect Ks/Vs before next tile's prologue
    }
}

extern "C" void kernel_launch(void* const* d_in, const int* in_sizes, int n_in,
                              void* d_out, int out_size, void* d_ws, size_t ws_size,
                              hipStream_t stream) {
    const void* x     = d_in[0];
    const void* Wqkv  = d_in[1];
    const void* bqkv  = d_in[2];
    const void* Wproj = d_in[3];
    const void* bproj = d_in[4];

    int* flag = (int*)d_ws;
    unsigned short* ws = (unsigned short*)d_ws + 8;
    unsigned short* WqkvT   = ws;                        // 3072*1024  (6 MB)
    unsigned short* WprojT  = WqkvT + 3072 * 1024;       // 1024*1024  (2 MB)
    unsigned short* q_ws    = WprojT + 1024 * 1024;      // 8M         (16 MB)
    unsigned short* kbf     = q_ws + 8 * 1024 * 1024;    // 8M         (16 MB)
    unsigned short* vbfT    = kbf + 8 * 1024 * 1024;     // 8M         (16 MB)
    unsigned short* amerged = vbfT + 8 * 1024 * 1024;    // 8M         (16 MB)
    unsigned short* xbf     = amerged;                   // ALIAS: xbf dead before attn writes amerged
    // total ws: ~72 MB

    sniff_k<<<1, 64, 0, stream>>>((const unsigned short*)x, flag);
    convert_x<<<dim3(8 * 1024 * 1024 / (256 * 8)), 256, 0, stream>>>(x, xbf, flag);
    transpose_k<<<dim3(3072 / 32, 1024 / 32), 256, 0, stream>>>(Wqkv, WqkvT, 1024, 3072, flag);
    transpose_k<<<dim3(1024 / 32, 1024 / 32), 256, 0, stream>>>(Wproj, WprojT, 1024, 1024, flag);
    gemm_bt<1><<<dim3(3072 / 128, 8192 / 128), 256, 0, stream>>>(
        xbf, WqkvT, bqkv, d_out, q_ws, kbf, vbfT, 8192, 3072, 1024, flag);
    attn<<<dim3(BB * NH * 4), 256, 0, stream>>>(q_ws, kbf, vbfT, amerged);
    gemm_bt<0><<<dim3(1024 / 128, 8192 / 128), 256, 0, stream>>>(
        amerged, WprojT, bproj, d_out, nullptr, nullptr, nullptr, 8192, 1024, 1024, flag);
}

// Round 8
// 374.968 us; speedup vs baseline: 1.1893x; 1.1893x over previous
//
#include <hip/hip_runtime.h>
#include <stdint.h>

// Problem: B=8, S=1024, NX=1024, H=16, D=64 (GPT-2 attention block)
// out = [ a: B*S*NX ][ present_k: B*H*S*D ][ present_v: B*H*S*D ]
// Input/output dtype sniffed at runtime (fp32 vs bf16); internals bf16.

#define BB 8
#define SS 1024
#define NXX 1024
#define NH 16
#define HD 64

typedef __bf16 bf16x8 __attribute__((ext_vector_type(8)));
typedef float  floatx4 __attribute__((ext_vector_type(4)));
typedef unsigned short ushort8 __attribute__((ext_vector_type(8)));
typedef unsigned short ushortx4 __attribute__((ext_vector_type(4)));  // 'ushort4' collides with HIP builtin

__device__ inline float bf2f(unsigned short u) {
    unsigned int x = ((unsigned int)u) << 16;
    float f;
    __builtin_memcpy(&f, &x, 4);
    return f;
}
__device__ inline unsigned short f2bf(float f) {
    unsigned int u;
    __builtin_memcpy(&u, &f, 4);
    u += 0x7FFFu + ((u >> 16) & 1u);  // RNE
    return (unsigned short)(u >> 16);
}

// async global->LDS, 16B per lane (dest = wave-uniform base + lane*16)
__device__ inline void gload_lds16(const unsigned short* g, unsigned short* l) {
    __builtin_amdgcn_global_load_lds(
        (const __attribute__((address_space(1))) void*)g,
        (__attribute__((address_space(3))) void*)l, 16, 0, 0);
}

// ---------------- dtype sniff: flag=1 if data is fp32, 0 if bf16 ----------------
__global__ void sniff_k(const unsigned short* __restrict__ x, int* __restrict__ flag) {
    if (threadIdx.x == 0 && blockIdx.x == 0) {
        int g = 0;
        for (int i = 0; i < 512; i++) {
            float f = bf2f(x[i]);
            float a = fabsf(f);
            if (!(a <= 1e4f)) g++;
            else if (f != 0.f && a < 1e-35f) g++;
        }
        *flag = (g > 16) ? 1 : 0;
    }
}

// ---------------- prep: convert_x + transpose(Wqkv) + transpose(Wproj) ----------
// blocks [0,4096): xbf = bf16(x), 8 elems/thread
// blocks [4096,7168): WqkvT[3072][1024] = Wqkv[1024][3072]^T (bf16)
// blocks [7168,8192): WprojT[1024][1024] = Wproj^T (bf16)
__global__ __launch_bounds__(256) void prep(
    const void* __restrict__ x, const void* __restrict__ Wqkv,
    const void* __restrict__ Wproj,
    unsigned short* __restrict__ xbf, unsigned short* __restrict__ WqkvT,
    unsigned short* __restrict__ WprojT, const int* __restrict__ flagp) {
    const int f32 = *flagp;
    int blk = blockIdx.x;
    if (blk < 4096) {
        const size_t i = ((size_t)blk * 256 + threadIdx.x) * 8;
        if (f32) {
            const floatx4* p = (const floatx4*)((const float*)x + i);
            floatx4 f0 = p[0], f1 = p[1];
            ushort8 u;
#pragma unroll
            for (int j = 0; j < 4; j++) { u[j] = f2bf(f0[j]); u[4 + j] = f2bf(f1[j]); }
            *(ushort8*)(xbf + i) = u;
        } else {
            *(ushort8*)(xbf + i) = *(const ushort8*)((const unsigned short*)x + i);
        }
        return;
    }
    blk -= 4096;
    const void* in;
    unsigned short* out;
    int R, C;
    if (blk < 3072) { in = Wqkv; out = WqkvT; R = 1024; C = 3072; }
    else            { blk -= 3072; in = Wproj; out = WprojT; R = 1024; C = 1024; }
    const int ctiles = C / 32;
    const int c0 = (blk % ctiles) * 32, r0 = (blk / ctiles) * 32;

    __shared__ unsigned short tile[32][33];
    const int tx = threadIdx.x & 31, ty = threadIdx.x >> 5;  // 32 x 8
    if (f32) {
        const float* inf = (const float*)in;
#pragma unroll
        for (int i = ty; i < 32; i += 8)
            tile[i][tx] = f2bf(inf[(size_t)(r0 + i) * C + c0 + tx]);
    } else {
        const unsigned short* inu = (const unsigned short*)in;
#pragma unroll
        for (int i = ty; i < 32; i += 8)
            tile[i][tx] = inu[(size_t)(r0 + i) * C + c0 + tx];
    }
    __syncthreads();
#pragma unroll
    for (int i = ty; i < 32; i += 8)
        out[(size_t)(c0 + i) * R + r0 + tx] = tile[tx][i];
}

// ---------------- transpose_v: vbfT[bh][d][sperm] <- d_out v region ------------
// One block per (bh, 64-s block). sperm within 64: ((s&15)<<2)|(s>>4).
__global__ __launch_bounds__(256) void transpose_v(
    const void* __restrict__ outbase, unsigned short* __restrict__ vbfT,
    const int* __restrict__ flagp) {
    const int f32 = *flagp;
    const int blk = blockIdx.x;
    const int sb = blk & 15;       // which 64-s block
    const int bh = blk >> 4;       // 0..127
    const int tid = threadIdx.x;
    const int r = tid >> 2;          // s within 64-block
    const int c0 = (tid & 3) * 16;   // d start
    __shared__ unsigned short tile[64][72];
    const int perm = ((r & 15) << 2) | (r >> 4);
    const size_t esz = f32 ? 4 : 2;
    const char* vbase = (const char*)outbase + (size_t)(2 * BB * SS * NXX) * esz;
    if (f32) {
        const float* src = (const float*)vbase + ((size_t)bh * SS + sb * 64 + r) * HD + c0;
#pragma unroll
        for (int j = 0; j < 16; j++) tile[c0 + j][perm] = f2bf(src[j]);
    } else {
        const unsigned short* src = (const unsigned short*)vbase + ((size_t)bh * SS + sb * 64 + r) * HD + c0;
#pragma unroll
        for (int j = 0; j < 16; j++) tile[c0 + j][perm] = src[j];
    }
    __syncthreads();
    const int d = tid >> 2;
    const int o0 = (tid & 3) * 16;
    unsigned short* dst = vbfT + ((size_t)(bh * HD + d)) * SS + sb * 64 + o0;
    *(ushort8*)dst       = *(const ushort8*)&tile[d][o0];
    *(ushort8*)(dst + 8) = *(const ushort8*)&tile[d][o0 + 8];
}

// ---------------- GEMM: C[M,N] = A[M,K] @ Bt[N,K]^T + bias[N] ----------------
// A, Bt: bf16. Staging via global_load_lds (16B/lane, m97 structure).
// MODE 0: writes `a` region of d_out in flag dtype.
// MODE 1: block-uniform section (col0>>10): q->q_ws bf16; k->d_out+kbf; v->d_out.
template <int MODE>
__global__ __launch_bounds__(256) void gemm_bt(
    const unsigned short* __restrict__ A,
    const unsigned short* __restrict__ Bt,
    const void* __restrict__ bias,
    void* __restrict__ outbase,
    unsigned short* __restrict__ q_ws,
    unsigned short* __restrict__ kbf,
    int M, int N, int K, const int* __restrict__ flagp) {
    __shared__ __align__(16) unsigned short As[128 * 32];
    __shared__ __align__(16) unsigned short Bs[128 * 32];

    const int f32 = *flagp;
    const int tid  = threadIdx.x;
    const int lane = tid & 63;
    const int wave = tid >> 6;
    const int wr = wave >> 1, wc = wave & 1;
    const int l15 = lane & 15;
    const int quad = lane >> 4;
    const int row0 = blockIdx.y * 128;
    const int col0 = blockIdx.x * 128;

    floatx4 acc[4][4];
    floatx4 zz = {0.f, 0.f, 0.f, 0.f};
#pragma unroll
    for (int i = 0; i < 4; i++)
#pragma unroll
        for (int j = 0; j < 4; j++) acc[i][j] = zz;

    const int lrow = lane >> 2;
    const int lcol = (lane & 3) * 8;
    const unsigned short* Ag = A  + (size_t)(row0 + wave * 32 + lrow) * K + lcol;
    const unsigned short* Bg = Bt + (size_t)(col0 + wave * 32 + lrow) * K + lcol;
    unsigned short* Asl0 = &As[(wave * 32) * 32];
    unsigned short* Asl1 = &As[(wave * 32 + 16) * 32];
    unsigned short* Bsl0 = &Bs[(wave * 32) * 32];
    unsigned short* Bsl1 = &Bs[(wave * 32 + 16) * 32];

    for (int k0 = 0; k0 < K; k0 += 32) {
        gload_lds16(Ag + k0, Asl0);
        gload_lds16(Ag + k0 + (size_t)16 * K, Asl1);
        gload_lds16(Bg + k0, Bsl0);
        gload_lds16(Bg + k0 + (size_t)16 * K, Bsl1);
        __syncthreads();

        bf16x8 af[4], bfr[4];
#pragma unroll
        for (int mi = 0; mi < 4; mi++)
            af[mi] = *(const bf16x8*)&As[(wr * 64 + mi * 16 + l15) * 32 + quad * 8];
#pragma unroll
        for (int ni = 0; ni < 4; ni++)
            bfr[ni] = *(const bf16x8*)&Bs[(wc * 64 + ni * 16 + l15) * 32 + quad * 8];
#pragma unroll
        for (int mi = 0; mi < 4; mi++)
#pragma unroll
            for (int ni = 0; ni < 4; ni++)
                acc[mi][ni] = __builtin_amdgcn_mfma_f32_16x16x32_bf16(af[mi], bfr[ni], acc[mi][ni], 0, 0, 0);
        __syncthreads();
    }

    float bv[4];
#pragma unroll
    for (int ni = 0; ni < 4; ni++) {
        const int colb = col0 + wc * 64 + ni * 16 + l15;
        bv[ni] = f32 ? ((const float*)bias)[colb] : bf2f(((const unsigned short*)bias)[colb]);
    }

    if (MODE == 0) {
#pragma unroll
        for (int mi = 0; mi < 4; mi++)
#pragma unroll
            for (int ni = 0; ni < 4; ni++) {
                const int colb = col0 + wc * 64 + ni * 16 + l15;
#pragma unroll
                for (int i = 0; i < 4; i++) {
                    const int row = row0 + wr * 64 + mi * 16 + quad * 4 + i;
                    const float val = acc[mi][ni][i] + bv[ni];
                    const size_t idx = (size_t)row * N + colb;
                    if (f32) ((float*)outbase)[idx] = val;
                    else     ((unsigned short*)outbase)[idx] = f2bf(val);
                }
            }
        return;
    }

    // MODE 1: section is block-uniform (col tile never straddles 1024 boundary)
    const int sec = col0 >> 10;
    const size_t esz = f32 ? 4 : 2;
    const int b = row0 >> 10;
    const int s0 = row0 & 1023;

    if (sec == 0) {
#pragma unroll
        for (int mi = 0; mi < 4; mi++)
#pragma unroll
            for (int ni = 0; ni < 4; ni++) {
                const int colb = col0 + wc * 64 + ni * 16 + l15;
                const int h = (colb & 1023) >> 6, d = colb & 63;
#pragma unroll
                for (int i = 0; i < 4; i++) {
                    const int s = s0 + wr * 64 + mi * 16 + quad * 4 + i;
                    q_ws[(size_t)((b * NH + h) * SS + s) * HD + d] = f2bf(acc[mi][ni][i] + bv[ni]);
                }
            }
    } else if (sec == 1) {
        char* kbase = (char*)outbase + (size_t)(BB * SS * NXX) * esz;
#pragma unroll
        for (int mi = 0; mi < 4; mi++)
#pragma unroll
            for (int ni = 0; ni < 4; ni++) {
                const int colb = col0 + wc * 64 + ni * 16 + l15;
                const int h = (colb & 1023) >> 6, d = colb & 63;
#pragma unroll
                for (int i = 0; i < 4; i++) {
                    const int s = s0 + wr * 64 + mi * 16 + quad * 4 + i;
                    const float val = acc[mi][ni][i] + bv[ni];
                    const size_t idx = (size_t)((b * NH + h) * SS + s) * HD + d;
                    if (f32) ((float*)kbase)[idx] = val;
                    else     ((unsigned short*)kbase)[idx] = f2bf(val);
                    kbf[idx] = f2bf(val);
                }
            }
    } else {
        char* vbase = (char*)outbase + (size_t)(2 * BB * SS * NXX) * esz;
#pragma unroll
        for (int mi = 0; mi < 4; mi++)
#pragma unroll
            for (int ni = 0; ni < 4; ni++) {
                const int colb = col0 + wc * 64 + ni * 16 + l15;
                const int h = (colb & 1023) >> 6, d = colb & 63;
#pragma unroll
                for (int i = 0; i < 4; i++) {
                    const int s = s0 + wr * 64 + mi * 16 + quad * 4 + i;
                    const float val = acc[mi][ni][i] + bv[ni];
                    const size_t idx = (size_t)((b * NH + h) * SS + s) * HD + d;
                    if (f32) ((float*)vbase)[idx] = val;
                    else     ((unsigned short*)vbase)[idx] = f2bf(val);
                }
            }
    }
}

// ---------------- flash attention: 4 waves/block, 2 paired Q-tiles/block ----------
// q_ws/kbf: [bh][s][d] bf16; vbfT: [bh][d][s] bf16 (key-permuted); amerged bf16.
__global__ __launch_bounds__(256) void attn(
    const unsigned short* __restrict__ q_ws,
    const unsigned short* __restrict__ kbf,
    const unsigned short* __restrict__ vbfT,
    unsigned short* __restrict__ amerged) {
    const int tid = threadIdx.x;
    const int lane = tid & 63;
    const int w = tid >> 6;
    const int l15 = lane & 15, quad = lane >> 4;
    const int blk = blockIdx.x;
    const int p = blk & 3;               // tile pair: {p, 7-p} (balanced: 18 units each)
    const int bh = blk >> 2;
    const int b = bh >> 4, h = bh & 15;

    const unsigned short* Q = q_ws + (size_t)bh * (SS * HD);
    const unsigned short* K = kbf + (size_t)bh * (SS * HD);
    const unsigned short* V = vbfT + (size_t)bh * (HD * SS);

    __shared__ __align__(16) unsigned short Ks[64][72];
    __shared__ __align__(16) unsigned short Vs[64][72];
    __shared__ __align__(16) unsigned short Pl[4][32][72];

    floatx4 zz = {0.f, 0.f, 0.f, 0.f};
    ushort8 ones_u;
#pragma unroll
    for (int j = 0; j < 8; j++) ones_u[j] = 0x3F80;  // bf16 1.0
    const bf16x8 ones = __builtin_bit_cast(bf16x8, ones_u);

    const int srow = tid >> 2;           // 0..63
    const int soff = (tid & 3) * 16;     // 0/16/32/48

#pragma unroll
    for (int tile = 0; tile < 2; tile++) {
        const int qb = tile ? (7 - p) : p;
        const int qbase = qb * 128;
        const int wrow0 = qbase + w * 32;
        const int wq_max = wrow0 + 31;
        const int jend = qbase + 128;

        bf16x8 qa[2][2];
#pragma unroll
        for (int m = 0; m < 2; m++)
#pragma unroll
            for (int t = 0; t < 2; t++)
                qa[m][t] = *(const bf16x8*)&Q[(size_t)(wrow0 + m * 16 + l15) * HD + t * 32 + quad * 8];

        floatx4 o[2][4], o5[2];
        float mrow[2][4];
#pragma unroll
        for (int m = 0; m < 2; m++) {
            o5[m] = zz;
#pragma unroll
            for (int i = 0; i < 4; i++) mrow[m][i] = -1e30f;
#pragma unroll
            for (int nf = 0; nf < 4; nf++) o[m][nf] = zz;
        }

        *(ushort8*)&Ks[srow][soff]     = *(const ushort8*)&K[(size_t)srow * HD + soff];
        *(ushort8*)&Ks[srow][soff + 8] = *(const ushort8*)&K[(size_t)srow * HD + soff + 8];
        *(ushort8*)&Vs[srow][soff]     = *(const ushort8*)&V[(size_t)srow * SS + soff];
        *(ushort8*)&Vs[srow][soff + 8] = *(const ushort8*)&V[(size_t)srow * SS + soff + 8];
        __syncthreads();

        for (int j0 = 0; j0 < jend; j0 += 64) {
            const bool havenext = (j0 + 64 < jend);
            ushort8 kn0, kn1, vn0, vn1;
            if (havenext) {
                kn0 = *(const ushort8*)&K[(size_t)(j0 + 64 + srow) * HD + soff];
                kn1 = *(const ushort8*)&K[(size_t)(j0 + 64 + srow) * HD + soff + 8];
                vn0 = *(const ushort8*)&V[(size_t)srow * SS + j0 + 64 + soff];
                vn1 = *(const ushort8*)&V[(size_t)srow * SS + j0 + 64 + soff + 8];
            }

            if (j0 <= wq_max) {
                floatx4 sf[2][4];
#pragma unroll
                for (int kg = 0; kg < 4; kg++) {
                    bf16x8 kb0 = *(const bf16x8*)&Ks[kg * 16 + l15][quad * 8];
                    bf16x8 kb1 = *(const bf16x8*)&Ks[kg * 16 + l15][32 + quad * 8];
#pragma unroll
                    for (int m = 0; m < 2; m++) {
                        floatx4 s = zz;
                        s = __builtin_amdgcn_mfma_f32_16x16x32_bf16(qa[m][0], kb0, s, 0, 0, 0);
                        s = __builtin_amdgcn_mfma_f32_16x16x32_bf16(qa[m][1], kb1, s, 0, 0, 0);
                        sf[m][kg] = s;
                    }
                }

                float alpha_[2][4];
#pragma unroll
                for (int m = 0; m < 2; m++)
#pragma unroll
                    for (int i = 0; i < 4; i++) {
                        const int qrow = wrow0 + m * 16 + quad * 4 + i;
                        float pv4[4];
#pragma unroll
                        for (int kg = 0; kg < 4; kg++) {
                            const int key = j0 + kg * 16 + l15;
                            float s = sf[m][kg][i] * 0.125f;
                            if (key > qrow) s = -10000.0f;
                            pv4[kg] = s;
                        }
                        float t = fmaxf(fmaxf(pv4[0], pv4[1]), fmaxf(pv4[2], pv4[3]));
                        t = fmaxf(t, __shfl_xor(t, 1));
                        t = fmaxf(t, __shfl_xor(t, 2));
                        t = fmaxf(t, __shfl_xor(t, 4));
                        t = fmaxf(t, __shfl_xor(t, 8));
                        const float mnew = fmaxf(mrow[m][i], t);
                        alpha_[m][i] = __expf(mrow[m][i] - mnew);
                        mrow[m][i] = mnew;
                        ushortx4 pk;
#pragma unroll
                        for (int kg = 0; kg < 4; kg++)
                            pk[kg] = f2bf(__expf(pv4[kg] - mnew));
                        *(ushortx4*)&Pl[w][m * 16 + quad * 4 + i][l15 * 4] = pk;
                    }

#pragma unroll
                for (int m = 0; m < 2; m++) {
#pragma unroll
                    for (int i = 0; i < 4; i++) o5[m][i] *= alpha_[m][i];
#pragma unroll
                    for (int nf = 0; nf < 4; nf++)
#pragma unroll
                        for (int i = 0; i < 4; i++) o[m][nf][i] *= alpha_[m][i];
                }

                bf16x8 pa[2][2];
#pragma unroll
                for (int m = 0; m < 2; m++) {
                    pa[m][0] = *(const bf16x8*)&Pl[w][m * 16 + l15][quad * 8];
                    pa[m][1] = *(const bf16x8*)&Pl[w][m * 16 + l15][32 + quad * 8];
                }

#pragma unroll
                for (int m = 0; m < 2; m++) {
                    o5[m] = __builtin_amdgcn_mfma_f32_16x16x32_bf16(pa[m][0], ones, o5[m], 0, 0, 0);
                    o5[m] = __builtin_amdgcn_mfma_f32_16x16x32_bf16(pa[m][1], ones, o5[m], 0, 0, 0);
                }
#pragma unroll
                for (int nf = 0; nf < 4; nf++) {
                    bf16x8 vb0 = *(const bf16x8*)&Vs[nf * 16 + l15][quad * 8];
                    bf16x8 vb1 = *(const bf16x8*)&Vs[nf * 16 + l15][32 + quad * 8];
#pragma unroll
                    for (int m = 0; m < 2; m++) {
                        o[m][nf] = __builtin_amdgcn_mfma_f32_16x16x32_bf16(pa[m][0], vb0, o[m][nf], 0, 0, 0);
                        o[m][nf] = __builtin_amdgcn_mfma_f32_16x16x32_bf16(pa[m][1], vb1, o[m][nf], 0, 0, 0);
                    }
                }
            }
            __syncthreads();
            if (havenext) {
                *(ushort8*)&Ks[srow][soff]     = kn0;
                *(ushort8*)&Ks[srow][soff + 8] = kn1;
                *(ushort8*)&Vs[srow][soff]     = vn0;
                *(ushort8*)&Vs[srow][soff + 8] = vn1;
            }
            __syncthreads();
        }

#pragma unroll
        for (int m = 0; m < 2; m++)
#pragma unroll
            for (int nf = 0; nf < 4; nf++)
#pragma unroll
                for (int i = 0; i < 4; i++) {
                    const int s = wrow0 + m * 16 + quad * 4 + i;
                    amerged[(size_t)(b * SS + s) * NXX + h * HD + nf * 16 + l15] =
                        f2bf(o[m][nf][i] / o5[m][i]);
                }
        __syncthreads();
    }
}

extern "C" void kernel_launch(void* const* d_in, const int* in_sizes, int n_in,
                              void* d_out, int out_size, void* d_ws, size_t ws_size,
                              hipStream_t stream) {
    const void* x     = d_in[0];
    const void* Wqkv  = d_in[1];
    const void* bqkv  = d_in[2];
    const void* Wproj = d_in[3];
    const void* bproj = d_in[4];

    int* flag = (int*)d_ws;
    unsigned short* ws = (unsigned short*)d_ws + 8;
    unsigned short* WqkvT   = ws;                        // 3072*1024  (6 MB)
    unsigned short* WprojT  = WqkvT + 3072 * 1024;       // 1024*1024  (2 MB)
    unsigned short* q_ws    = WprojT + 1024 * 1024;      // 8M         (16 MB)
    unsigned short* kbf     = q_ws + 8 * 1024 * 1024;    // 8M         (16 MB)
    unsigned short* vbfT    = kbf + 8 * 1024 * 1024;     // 8M         (16 MB)
    unsigned short* amerged = vbfT + 8 * 1024 * 1024;    // 8M         (16 MB)
    unsigned short* xbf     = amerged;                   // ALIAS: xbf dead before attn writes amerged
    // total ws: ~72 MB

    sniff_k<<<1, 64, 0, stream>>>((const unsigned short*)x, flag);
    prep<<<dim3(8192), 256, 0, stream>>>(x, Wqkv, Wproj, xbf, WqkvT, WprojT, flag);
    gemm_bt<1><<<dim3(3072 / 128, 8192 / 128), 256, 0, stream>>>(
        xbf, WqkvT, bqkv, d_out, q_ws, kbf, 8192, 3072, 1024, flag);
    transpose_v<<<dim3(128 * 16), 256, 0, stream>>>(d_out, vbfT, flag);
    attn<<<dim3(BB * NH * 4), 256, 0, stream>>>(q_ws, kbf, vbfT, amerged);
    gemm_bt<0><<<dim3(1024 / 128, 8192 / 128), 256, 0, stream>>>(
        amerged, WprojT, bproj, d_out, nullptr, nullptr, 8192, 1024, 1024, flag);
}